// Round 10
// baseline (1040.190 us; speedup 1.0000x reference)
//
#include <hip/hip_runtime.h>
#include <stdint.h>

constexpr int kN    = 100000;   // nodes
constexpr int kDOut = 128;      // output dim
constexpr int kDIn  = 256;      // input feature dim
constexpr int kNNZ  = 3200000;  // nnz for both X and A
constexpr float kInvKeep = (float)(1.0 / 0.9);

constexpr int kBShift = 15;                       // coarse bucket = 32768 rows
constexpr int kNBkt   = (kN + (1 << kBShift) - 1) >> kBShift;   // 4
constexpr int kPassBBlocks = 4883;                // covers 1.25M edges/bucket

// ---------------- RNG (verified round 4: partitionable, bits = o0^o1) -----
__device__ __forceinline__ uint32_t rotl32(uint32_t v, int r) {
  return (v << r) | (v >> (32 - r));
}
__device__ __forceinline__ void threefry2x32(uint32_t k0, uint32_t k1,
                                             uint32_t x0, uint32_t x1,
                                             uint32_t& o0, uint32_t& o1) {
  const uint32_t ks0 = k0, ks1 = k1, ks2 = k0 ^ k1 ^ 0x1BD11BDAu;
  x0 += ks0; x1 += ks1;
#define TF_RND(r) { x0 += x1; x1 = rotl32(x1, (r)); x1 ^= x0; }
  TF_RND(13) TF_RND(15) TF_RND(26) TF_RND(6)
  x0 += ks1; x1 += ks2 + 1u;
  TF_RND(17) TF_RND(29) TF_RND(16) TF_RND(24)
  x0 += ks2; x1 += ks0 + 2u;
  TF_RND(13) TF_RND(15) TF_RND(26) TF_RND(6)
  x0 += ks0; x1 += ks1 + 3u;
  TF_RND(17) TF_RND(29) TF_RND(16) TF_RND(24)
  x0 += ks1; x1 += ks2 + 4u;
  TF_RND(13) TF_RND(15) TF_RND(26) TF_RND(6)
  x0 += ks2; x1 += ks0 + 5u;
#undef TF_RND
  o0 = x0; o1 = x1;
}
__device__ __forceinline__ float keep_mask(uint32_t i) {
  uint32_t o0, o1;
  threefry2x32(0u, 42u, 0u, i, o0, o1);
  uint32_t bits = o0 ^ o1;
  float u = __uint_as_float((bits >> 9) | 0x3f800000u) - 1.0f;
  return floorf(0.9f + u);
}

// ---------------- bf16 helpers (RTNE) --------------------------------------
__device__ __forceinline__ uint16_t f32_to_bf16(float f) {
  uint32_t u = __float_as_uint(f);
  u += 0x7fffu + ((u >> 16) & 1u);
  return (uint16_t)(u >> 16);
}
__device__ __forceinline__ float bf16lo_to_f32(uint32_t packed) {
  return __uint_as_float(packed << 16);
}
__device__ __forceinline__ float bf16hi_to_f32(uint32_t packed) {
  return __uint_as_float(packed & 0xffff0000u);
}

// ---------------- hist -> scan (CSR rowptr) --------------------------------
template<bool DROPOUT>
__global__ void hist_kernel(const int* __restrict__ rows, int* __restrict__ cnt,
                            int nnz) {
  int e = blockIdx.x * blockDim.x + threadIdx.x;
  if (e >= nnz) return;
  if (DROPOUT && keep_mask((uint32_t)e) == 0.0f) return;
  atomicAdd(&cnt[rows[e]], 1);
}

constexpr int kScanChunk = 2048;   // 256 threads x 8 elems
constexpr int kScanBlk   = (kN + kScanChunk - 1) / kScanChunk;  // 49

__global__ void scan1_kernel(const int* __restrict__ cnt, int* __restrict__ rowptr,
                             int* __restrict__ partials, int n) {
  __shared__ int sd[256];
  int b = blockIdx.x, t = threadIdx.x;
  int base = b * kScanChunk + t * 8;
  int v[8]; int s = 0;
  #pragma unroll
  for (int k = 0; k < 8; ++k) { int idx = base + k; v[k] = (idx < n) ? cnt[idx] : 0; s += v[k]; }
  sd[t] = s; __syncthreads();
  #pragma unroll
  for (int off = 1; off < 256; off <<= 1) {
    int x = (t >= off) ? sd[t - off] : 0;
    __syncthreads();
    sd[t] += x;
    __syncthreads();
  }
  if (t == 255) partials[b] = sd[255];
  int run = (t == 0) ? 0 : sd[t - 1];
  #pragma unroll
  for (int k = 0; k < 8; ++k) { int idx = base + k; if (idx < n) rowptr[idx] = run; run += v[k]; }
}

__global__ void scan2_kernel(int* __restrict__ partials, int* __restrict__ rowptr,
                             int nblk, int n) {
  __shared__ int sd[64];
  int t = threadIdx.x;
  sd[t] = (t < nblk) ? partials[t] : 0;
  __syncthreads();
  #pragma unroll
  for (int off = 1; off < 64; off <<= 1) {
    int x = (t >= off) ? sd[t - off] : 0;
    __syncthreads();
    sd[t] += x;
    __syncthreads();
  }
  if (t < nblk) partials[t] = (t == 0) ? 0 : sd[t - 1];
  if (t == 63) rowptr[n] = sd[63];
}

// finalize rowptr; seed cur = rowptr; seed coarse-bucket cursors
__global__ void scan3_kernel(int* __restrict__ rowptr, int* __restrict__ cur,
                             int* __restrict__ bcur,
                             const int* __restrict__ partials, int n) {
  int i = blockIdx.x * blockDim.x + threadIdx.x;
  if (i < n) {
    int v = rowptr[i] + partials[i / kScanChunk];
    rowptr[i] = v;
    cur[i] = v;
    if ((i & ((1 << kBShift) - 1)) == 0) bcur[i >> kBShift] = v;
  }
}

// ---------------- passA: coarse 4-bucket partition --------------------------
// 256 thr x 16 edges per block. Block-level reservation via LDS int counts
// (native ds_add) + 4 global atomics per block. Record: (rl<<17 | col, val).
template<bool DROPOUT>
__global__ void __launch_bounds__(256) passA_kernel(
    const int* __restrict__ rows, const int* __restrict__ cols,
    const float* __restrict__ vals, int* __restrict__ bcur,
    uint2* __restrict__ P, int nnz) {
  __shared__ int lcnt[kNBkt];
  __shared__ int gbase[kNBkt];
  const int tid = threadIdx.x;
  const int base = blockIdx.x * 4096;
  if (tid < kNBkt) lcnt[tid] = 0;
  __syncthreads();
  // phase 1: count per bucket (register counters, static names - rule #20)
  int c0 = 0, c1 = 0, c2 = 0, c3 = 0;
  for (int i = 0; i < 16; ++i) {
    int e = base + i * 256 + tid;
    if (e < nnz) {
      if (!DROPOUT || keep_mask((uint32_t)e) != 0.0f) {
        int b = rows[e] >> kBShift;
        c0 += (b == 0); c1 += (b == 1); c2 += (b == 2); c3 += (b == 3);
      }
    }
  }
  if (c0) atomicAdd(&lcnt[0], c0);
  if (c1) atomicAdd(&lcnt[1], c1);
  if (c2) atomicAdd(&lcnt[2], c2);
  if (c3) atomicAdd(&lcnt[3], c3);
  __syncthreads();
  if (tid < kNBkt) {
    gbase[tid] = atomicAdd(&bcur[tid], lcnt[tid]);
    lcnt[tid] = 0;   // reuse as intra-block cursor
  }
  __syncthreads();
  // phase 2: append
  for (int i = 0; i < 16; ++i) {
    int e = base + i * 256 + tid;
    if (e >= nnz) continue;
    float v = vals[e];
    if (DROPOUT) {
      if (keep_mask((uint32_t)e) == 0.0f) continue;
      v *= kInvKeep;
    }
    int r = rows[e];
    int b = r >> kBShift;
    int lpos = atomicAdd(&lcnt[b], 1);
    uint2 rec;
    rec.x = ((uint32_t)(r & ((1 << kBShift) - 1)) << 17) | (uint32_t)cols[e];
    rec.y = __float_as_uint(v);
    P[gbase[b] + lpos] = rec;
  }
}

// ---------------- passB: fine scatter within one coarse bucket -------------
__global__ void passB_kernel(const int* __restrict__ rowptr,
                             const uint2* __restrict__ P,
                             int* __restrict__ cur,
                             uint2* __restrict__ Q, int lorow, int hirow) {
  int s = rowptr[lorow];
  int t = rowptr[hirow];
  int idx = s + blockIdx.x * 256 + threadIdx.x;
  if (idx >= t) return;
  uint2 rec = P[idx];
  int r = lorow + (int)(rec.x >> 17);
  int pos = atomicAdd(&cur[r], 1);
  uint2 q; q.x = rec.x & 0x1FFFFu; q.y = rec.y;
  Q[pos] = q;
}

// ---------------- fallback single-pass scatter (round-6 validated) ---------
template<bool DROPOUT>
__global__ void scatter_kernel(const int* __restrict__ rows,
                               const int* __restrict__ cols,
                               const float* __restrict__ vals,
                               int* __restrict__ cur,
                               uint2* __restrict__ spack, int nnz) {
  int e = blockIdx.x * blockDim.x + threadIdx.x;
  if (e >= nnz) return;
  float v = vals[e];
  if (DROPOUT) {
    if (keep_mask((uint32_t)e) == 0.0f) return;
    v *= kInvKeep;
  }
  int pos = atomicAdd(&cur[rows[e]], 1);
  uint2 p; p.x = (uint32_t)cols[e]; p.y = __float_as_uint(v);
  spack[pos] = p;
}

// ---------------- W (f32, [kDIn][kDOut]) -> bf16 copy ----------------------
__global__ void wcvt_kernel(const float* __restrict__ W, uint16_t* __restrict__ Wb) {
  int i = blockIdx.x * blockDim.x + threadIdx.x;
  if (i < kDIn * kDOut) Wb[i] = f32_to_bf16(W[i]);
}

// ---------------- CSR SpMM, bf16 B-matrix, 4-deep edge unroll --------------
// 4 rows per 256-thread block; 64 lanes/row; lane computes d=2*lane, 2*lane+1
// via one 4B bf16x2 gather per edge.
template<bool OUT_BF16, bool RELU>
__global__ void spmm_csr_kernel(const int* __restrict__ rowptr,
                                const uint2* __restrict__ spack,
                                const uint16_t* __restrict__ B,  // bf16 [*, kDOut]
                                void* __restrict__ outv, int nrows) {
  int tid = threadIdx.x;
  int row = blockIdx.x * 4 + (tid >> 6);
  int lane = tid & 63;
  if (row >= nrows) return;
  int e = rowptr[row], e_end = rowptr[row + 1];
  float a0 = 0.0f, a1 = 0.0f;
  const int doff = lane * 2;
  for (; e + 3 < e_end; e += 4) {
    uint2 p0 = spack[e],     p1 = spack[e + 1];
    uint2 p2 = spack[e + 2], p3 = spack[e + 3];
    uint32_t g0 = *(const uint32_t*)(B + (size_t)p0.x * kDOut + doff);
    uint32_t g1 = *(const uint32_t*)(B + (size_t)p1.x * kDOut + doff);
    uint32_t g2 = *(const uint32_t*)(B + (size_t)p2.x * kDOut + doff);
    uint32_t g3 = *(const uint32_t*)(B + (size_t)p3.x * kDOut + doff);
    float v0 = __uint_as_float(p0.y), v1 = __uint_as_float(p1.y);
    float v2 = __uint_as_float(p2.y), v3 = __uint_as_float(p3.y);
    a0 += v0 * bf16lo_to_f32(g0); a1 += v0 * bf16hi_to_f32(g0);
    a0 += v1 * bf16lo_to_f32(g1); a1 += v1 * bf16hi_to_f32(g1);
    a0 += v2 * bf16lo_to_f32(g2); a1 += v2 * bf16hi_to_f32(g2);
    a0 += v3 * bf16lo_to_f32(g3); a1 += v3 * bf16hi_to_f32(g3);
  }
  for (; e < e_end; ++e) {
    uint2 p0 = spack[e];
    float v0 = __uint_as_float(p0.y);
    uint32_t g0 = *(const uint32_t*)(B + (size_t)p0.x * kDOut + doff);
    a0 += v0 * bf16lo_to_f32(g0);
    a1 += v0 * bf16hi_to_f32(g0);
  }
  if (RELU) { a0 = fmaxf(a0, 0.0f); a1 = fmaxf(a1, 0.0f); }
  if (OUT_BF16) {
    uint32_t packed = (uint32_t)f32_to_bf16(a0) | ((uint32_t)f32_to_bf16(a1) << 16);
    ((uint32_t*)outv)[(size_t)row * (kDOut / 2) + lane] = packed;
  } else {
    float2 o; o.x = a0; o.y = a1;
    ((float2*)outv)[(size_t)row * (kDOut / 2) + lane] = o;
  }
}

// ---------------------------------------------------------------------------
extern "C" void kernel_launch(void* const* d_in, const int* in_sizes, int n_in,
                              void* d_out, int out_size, void* d_ws, size_t ws_size,
                              hipStream_t stream) {
  const int*   x_rows   = (const int*)d_in[0];
  const int*   x_cols   = (const int*)d_in[1];
  const float* x_vals   = (const float*)d_in[2];
  const int*   adj_rows = (const int*)d_in[3];
  const int*   adj_cols = (const int*)d_in[4];
  const float* adj_vals = (const float*)d_in[5];
  const float* W        = (const float*)d_in[6];
  float* out = (float*)d_out;

  // workspace layout (256B-aligned chunks)
  size_t off = 0;
  auto take = [&](size_t bytes) -> char* {
    char* p = (char*)d_ws + off;
    off += (bytes + 255) & ~(size_t)255;
    return p;
  };
  uint16_t* hb     = (uint16_t*)take((size_t)kN * kDOut * 2);   // 25.6 MB (bf16 h)
  uint16_t* Wb     = (uint16_t*)take((size_t)kDIn * kDOut * 2); // 64 KB
  int*      rowptr = (int*)take((size_t)(kN + 1) * 4);          // 400 KB
  int*      cur    = (int*)take((size_t)kN * 4);                // 400 KB
  int*      bcur   = (int*)take(kNBkt * 4);
  int*      partials = (int*)take(64 * 4);
  uint2*    Q      = (uint2*)take((size_t)kNNZ * 8);            // 25.6 MB (CSR spack)
  const size_t baseNeeded = off;                                // ~52.1 MB
  uint2*    P      = (uint2*)take((size_t)kNNZ * 8);            // 25.6 MB (coarse)
  const size_t fullNeeded = off;                                // ~77.7 MB
  if (ws_size < baseNeeded) return;
  const bool twoPhase = (ws_size >= fullNeeded);

  const int edgeBlocks  = (kNNZ + 255) / 256;
  const int passABlocks = (kNNZ + 4095) / 4096;
  const int spmmBlocks  = (kN + 3) / 4;

  wcvt_kernel<<<(kDIn * kDOut + 255) / 256, 256, 0, stream>>>(W, Wb);

  // ---------- X: CSR build (dropout folded) + spmm1 -> hb ----------
  hipMemsetAsync(cur, 0, (size_t)kN * 4, stream);
  hist_kernel<true><<<edgeBlocks, 256, 0, stream>>>(x_rows, cur, kNNZ);
  scan1_kernel<<<kScanBlk, 256, 0, stream>>>(cur, rowptr, partials, kN);
  scan2_kernel<<<1, 64, 0, stream>>>(partials, rowptr, kScanBlk, kN);
  scan3_kernel<<<(kN + 255) / 256, 256, 0, stream>>>(rowptr, cur, bcur, partials, kN);
  if (twoPhase) {
    passA_kernel<true><<<passABlocks, 256, 0, stream>>>(
        x_rows, x_cols, x_vals, bcur, P, kNNZ);
    for (int k = 0; k < kNBkt; ++k) {
      int lo = k << kBShift;
      int hi = (lo + (1 << kBShift) < kN) ? lo + (1 << kBShift) : kN;
      passB_kernel<<<kPassBBlocks, 256, 0, stream>>>(rowptr, P, cur, Q, lo, hi);
    }
  } else {
    scatter_kernel<true><<<edgeBlocks, 256, 0, stream>>>(
        x_rows, x_cols, x_vals, cur, Q, kNNZ);
  }
  spmm_csr_kernel<true, false><<<spmmBlocks, 256, 0, stream>>>(
      rowptr, Q, Wb, hb, kN);

  // ---------- adj: CSR build + spmm2(+relu) -> out ----------
  hipMemsetAsync(cur, 0, (size_t)kN * 4, stream);
  hist_kernel<false><<<edgeBlocks, 256, 0, stream>>>(adj_rows, cur, kNNZ);
  scan1_kernel<<<kScanBlk, 256, 0, stream>>>(cur, rowptr, partials, kN);
  scan2_kernel<<<1, 64, 0, stream>>>(partials, rowptr, kScanBlk, kN);
  scan3_kernel<<<(kN + 255) / 256, 256, 0, stream>>>(rowptr, cur, bcur, partials, kN);
  if (twoPhase) {
    passA_kernel<false><<<passABlocks, 256, 0, stream>>>(
        adj_rows, adj_cols, adj_vals, bcur, P, kNNZ);
    for (int k = 0; k < kNBkt; ++k) {
      int lo = k << kBShift;
      int hi = (lo + (1 << kBShift) < kN) ? lo + (1 << kBShift) : kN;
      passB_kernel<<<kPassBBlocks, 256, 0, stream>>>(rowptr, P, cur, Q, lo, hi);
    }
  } else {
    scatter_kernel<false><<<edgeBlocks, 256, 0, stream>>>(
        adj_rows, adj_cols, adj_vals, cur, Q, kNNZ);
  }
  spmm_csr_kernel<false, true><<<spmmBlocks, 256, 0, stream>>>(
      rowptr, Q, hb, out, kN);
}

// Round 11
// 951.260 us; speedup vs baseline: 1.0935x; 1.0935x over previous
//
#include <hip/hip_runtime.h>
#include <stdint.h>

constexpr int kN    = 100000;   // nodes
constexpr int kDOut = 128;      // output dim
constexpr int kDIn  = 256;      // input feature dim
constexpr int kNNZ  = 3200000;  // nnz for both X and A
constexpr float kInvKeep = (float)(1.0 / 0.9);
constexpr int kCopies = 8;      // one counter copy per XCD (blockIdx & 7)

// ---------------- RNG (verified round 4: partitionable, bits = o0^o1) -----
__device__ __forceinline__ uint32_t rotl32(uint32_t v, int r) {
  return (v << r) | (v >> (32 - r));
}
__device__ __forceinline__ void threefry2x32(uint32_t k0, uint32_t k1,
                                             uint32_t x0, uint32_t x1,
                                             uint32_t& o0, uint32_t& o1) {
  const uint32_t ks0 = k0, ks1 = k1, ks2 = k0 ^ k1 ^ 0x1BD11BDAu;
  x0 += ks0; x1 += ks1;
#define TF_RND(r) { x0 += x1; x1 = rotl32(x1, (r)); x1 ^= x0; }
  TF_RND(13) TF_RND(15) TF_RND(26) TF_RND(6)
  x0 += ks1; x1 += ks2 + 1u;
  TF_RND(17) TF_RND(29) TF_RND(16) TF_RND(24)
  x0 += ks2; x1 += ks0 + 2u;
  TF_RND(13) TF_RND(15) TF_RND(26) TF_RND(6)
  x0 += ks0; x1 += ks1 + 3u;
  TF_RND(17) TF_RND(29) TF_RND(16) TF_RND(24)
  x0 += ks1; x1 += ks2 + 4u;
  TF_RND(13) TF_RND(15) TF_RND(26) TF_RND(6)
  x0 += ks2; x1 += ks0 + 5u;
#undef TF_RND
  o0 = x0; o1 = x1;
}
__device__ __forceinline__ float keep_mask(uint32_t i) {
  uint32_t o0, o1;
  threefry2x32(0u, 42u, 0u, i, o0, o1);
  uint32_t bits = o0 ^ o1;
  float u = __uint_as_float((bits >> 9) | 0x3f800000u) - 1.0f;
  return floorf(0.9f + u);
}

// ---------------- bf16 helpers (RTNE) --------------------------------------
__device__ __forceinline__ uint16_t f32_to_bf16(float f) {
  uint32_t u = __float_as_uint(f);
  u += 0x7fffu + ((u >> 16) & 1u);
  return (uint16_t)(u >> 16);
}
__device__ __forceinline__ float bf16lo_to_f32(uint32_t packed) {
  return __uint_as_float(packed << 16);
}
__device__ __forceinline__ float bf16hi_to_f32(uint32_t packed) {
  return __uint_as_float(packed & 0xffff0000u);
}

// ---------------- XCD-privatized histogram ---------------------------------
// copy k = blockIdx & 7: with round-robin block->XCD dispatch, all atomics to
// copy k come from one XCD -> counter lines stay in that XCD's L2.
template<bool DROPOUT>
__global__ void hist8_kernel(const int* __restrict__ rows, int* __restrict__ cnt8,
                             int nnz) {
  int e = blockIdx.x * blockDim.x + threadIdx.x;
  if (e >= nnz) return;
  if (DROPOUT && keep_mask((uint32_t)e) == 0.0f) return;
  int k = blockIdx.x & (kCopies - 1);
  atomicAdd(&cnt8[k * kN + rows[e]], 1);
}

// ---------------- scan over summed copies ----------------------------------
constexpr int kScanChunk = 2048;   // 256 threads x 8 elems
constexpr int kScanBlk   = (kN + kScanChunk - 1) / kScanChunk;  // 49

__global__ void scan1_kernel(const int* __restrict__ cnt8, int* __restrict__ rowptr,
                             int* __restrict__ partials, int n) {
  __shared__ int sd[256];
  int b = blockIdx.x, t = threadIdx.x;
  int base = b * kScanChunk + t * 8;
  int v[8]; int s = 0;
  #pragma unroll
  for (int k = 0; k < 8; ++k) {
    int idx = base + k;
    int c = 0;
    if (idx < n) {
      #pragma unroll
      for (int j = 0; j < kCopies; ++j) c += cnt8[j * kN + idx];
    }
    v[k] = c; s += c;
  }
  sd[t] = s; __syncthreads();
  #pragma unroll
  for (int off = 1; off < 256; off <<= 1) {
    int x = (t >= off) ? sd[t - off] : 0;
    __syncthreads();
    sd[t] += x;
    __syncthreads();
  }
  if (t == 255) partials[b] = sd[255];
  int run = (t == 0) ? 0 : sd[t - 1];
  #pragma unroll
  for (int k = 0; k < 8; ++k) { int idx = base + k; if (idx < n) rowptr[idx] = run; run += v[k]; }
}

__global__ void scan2_kernel(int* __restrict__ partials, int* __restrict__ rowptr,
                             int nblk, int n) {
  __shared__ int sd[64];
  int t = threadIdx.x;
  sd[t] = (t < nblk) ? partials[t] : 0;
  __syncthreads();
  #pragma unroll
  for (int off = 1; off < 64; off <<= 1) {
    int x = (t >= off) ? sd[t - off] : 0;
    __syncthreads();
    sd[t] += x;
    __syncthreads();
  }
  if (t < nblk) partials[t] = (t == 0) ? 0 : sd[t - 1];
  if (t == 63) rowptr[n] = sd[63];
}

// finalize rowptr; emit per-copy cursors: cur8[k][i] = rowptr[i] + prefix_k
__global__ void scan3_kernel(int* __restrict__ rowptr, int* __restrict__ cur8,
                             const int* __restrict__ cnt8,
                             const int* __restrict__ partials, int n) {
  int i = blockIdx.x * blockDim.x + threadIdx.x;
  if (i >= n) return;
  int v = rowptr[i] + partials[i / kScanChunk];
  rowptr[i] = v;
  int run = v;
  #pragma unroll
  for (int k = 0; k < kCopies; ++k) {
    cur8[k * kN + i] = run;
    run += cnt8[k * kN + i];
  }
}

// ---------------- scatter with XCD-local cursors ----------------------------
// Same grid as hist8 -> same copy k per edge -> counts match sub-ranges.
template<bool DROPOUT>
__global__ void scatter_kernel(const int* __restrict__ rows,
                               const int* __restrict__ cols,
                               const float* __restrict__ vals,
                               int* __restrict__ cur8,
                               uint2* __restrict__ spack, int nnz) {
  int e = blockIdx.x * blockDim.x + threadIdx.x;
  if (e >= nnz) return;
  float v = vals[e];
  if (DROPOUT) {
    if (keep_mask((uint32_t)e) == 0.0f) return;
    v *= kInvKeep;
  }
  int k = blockIdx.x & (kCopies - 1);
  int pos = atomicAdd(&cur8[k * kN + rows[e]], 1);
  uint2 p;
  p.x = (uint32_t)cols[e];
  p.y = __float_as_uint(v);
  spack[pos] = p;
}

// ---------------- W (f32, [kDIn][kDOut]) -> bf16 copy ----------------------
__global__ void wcvt_kernel(const float* __restrict__ W, uint16_t* __restrict__ Wb) {
  int i = blockIdx.x * blockDim.x + threadIdx.x;
  if (i < kDIn * kDOut) Wb[i] = f32_to_bf16(W[i]);
}

// ---------------- CSR SpMM, bf16 B-matrix, 4-deep edge unroll --------------
// 4 rows per 256-thread block; 64 lanes/row; lane computes d=2*lane, 2*lane+1
// via one 4B bf16x2 load per edge (wave reads a contiguous 256B B-row slice).
template<bool OUT_BF16, bool RELU>
__global__ void spmm_csr_kernel(const int* __restrict__ rowptr,
                                const uint2* __restrict__ spack,
                                const uint16_t* __restrict__ B,  // bf16 [*, kDOut]
                                void* __restrict__ outv, int nrows) {
  int tid = threadIdx.x;
  int row = blockIdx.x * 4 + (tid >> 6);
  int lane = tid & 63;
  if (row >= nrows) return;
  int e = rowptr[row], e_end = rowptr[row + 1];
  float a0 = 0.0f, a1 = 0.0f;
  const int doff = lane * 2;
  for (; e + 3 < e_end; e += 4) {
    uint2 p0 = spack[e],     p1 = spack[e + 1];
    uint2 p2 = spack[e + 2], p3 = spack[e + 3];
    uint32_t g0 = *(const uint32_t*)(B + (size_t)p0.x * kDOut + doff);
    uint32_t g1 = *(const uint32_t*)(B + (size_t)p1.x * kDOut + doff);
    uint32_t g2 = *(const uint32_t*)(B + (size_t)p2.x * kDOut + doff);
    uint32_t g3 = *(const uint32_t*)(B + (size_t)p3.x * kDOut + doff);
    float v0 = __uint_as_float(p0.y), v1 = __uint_as_float(p1.y);
    float v2 = __uint_as_float(p2.y), v3 = __uint_as_float(p3.y);
    a0 += v0 * bf16lo_to_f32(g0); a1 += v0 * bf16hi_to_f32(g0);
    a0 += v1 * bf16lo_to_f32(g1); a1 += v1 * bf16hi_to_f32(g1);
    a0 += v2 * bf16lo_to_f32(g2); a1 += v2 * bf16hi_to_f32(g2);
    a0 += v3 * bf16lo_to_f32(g3); a1 += v3 * bf16hi_to_f32(g3);
  }
  for (; e < e_end; ++e) {
    uint2 p0 = spack[e];
    float v0 = __uint_as_float(p0.y);
    uint32_t g0 = *(const uint32_t*)(B + (size_t)p0.x * kDOut + doff);
    a0 += v0 * bf16lo_to_f32(g0);
    a1 += v0 * bf16hi_to_f32(g0);
  }
  if (RELU) { a0 = fmaxf(a0, 0.0f); a1 = fmaxf(a1, 0.0f); }
  if (OUT_BF16) {
    uint32_t packed = (uint32_t)f32_to_bf16(a0) | ((uint32_t)f32_to_bf16(a1) << 16);
    ((uint32_t*)outv)[(size_t)row * (kDOut / 2) + lane] = packed;
  } else {
    float2 o; o.x = a0; o.y = a1;
    ((float2*)outv)[(size_t)row * (kDOut / 2) + lane] = o;
  }
}

// ---------------------------------------------------------------------------
extern "C" void kernel_launch(void* const* d_in, const int* in_sizes, int n_in,
                              void* d_out, int out_size, void* d_ws, size_t ws_size,
                              hipStream_t stream) {
  const int*   x_rows   = (const int*)d_in[0];
  const int*   x_cols   = (const int*)d_in[1];
  const float* x_vals   = (const float*)d_in[2];
  const int*   adj_rows = (const int*)d_in[3];
  const int*   adj_cols = (const int*)d_in[4];
  const float* adj_vals = (const float*)d_in[5];
  const float* W        = (const float*)d_in[6];
  float* out = (float*)d_out;

  // workspace layout (256B-aligned chunks)
  size_t off = 0;
  auto take = [&](size_t bytes) -> char* {
    char* p = (char*)d_ws + off;
    off += (bytes + 255) & ~(size_t)255;
    return p;
  };
  uint16_t* hb     = (uint16_t*)take((size_t)kN * kDOut * 2);       // 25.6 MB
  uint16_t* Wb     = (uint16_t*)take((size_t)kDIn * kDOut * 2);     // 64 KB
  int*      rowptr = (int*)take((size_t)(kN + 1) * 4);              // 400 KB
  int*      cnt8   = (int*)take((size_t)kCopies * kN * 4);          // 3.2 MB
  int*      cur8   = (int*)take((size_t)kCopies * kN * 4);          // 3.2 MB
  int*      partials = (int*)take(64 * 4);
  uint2*    spack  = (uint2*)take((size_t)kNNZ * 8);                // 25.6 MB
  const size_t needed = off;                                        // ~58.1 MB
  if (ws_size < needed) return;  // round-5 proved ws >= 77.7 MB

  const int edgeBlocks = (kNNZ + 255) / 256;
  const int spmmBlocks = (kN + 3) / 4;

  wcvt_kernel<<<(kDIn * kDOut + 255) / 256, 256, 0, stream>>>(W, Wb);

  // ---------- X: CSR build (dropout folded) + spmm1 -> hb ----------
  hipMemsetAsync(cnt8, 0, (size_t)kCopies * kN * 4, stream);
  hist8_kernel<true><<<edgeBlocks, 256, 0, stream>>>(x_rows, cnt8, kNNZ);
  scan1_kernel<<<kScanBlk, 256, 0, stream>>>(cnt8, rowptr, partials, kN);
  scan2_kernel<<<1, 64, 0, stream>>>(partials, rowptr, kScanBlk, kN);
  scan3_kernel<<<(kN + 255) / 256, 256, 0, stream>>>(rowptr, cur8, cnt8, partials, kN);
  scatter_kernel<true><<<edgeBlocks, 256, 0, stream>>>(
      x_rows, x_cols, x_vals, cur8, spack, kNNZ);
  spmm_csr_kernel<true, false><<<spmmBlocks, 256, 0, stream>>>(
      rowptr, spack, Wb, hb, kN);

  // ---------- adj: CSR build (reuse buffers) + spmm2(+relu) -> out ----------
  hipMemsetAsync(cnt8, 0, (size_t)kCopies * kN * 4, stream);
  hist8_kernel<false><<<edgeBlocks, 256, 0, stream>>>(adj_rows, cnt8, kNNZ);
  scan1_kernel<<<kScanBlk, 256, 0, stream>>>(cnt8, rowptr, partials, kN);
  scan2_kernel<<<1, 64, 0, stream>>>(partials, rowptr, kScanBlk, kN);
  scan3_kernel<<<(kN + 255) / 256, 256, 0, stream>>>(rowptr, cur8, cnt8, partials, kN);
  scatter_kernel<false><<<edgeBlocks, 256, 0, stream>>>(
      adj_rows, adj_cols, adj_vals, cur8, spack, kNNZ);
  spmm_csr_kernel<false, true><<<spmmBlocks, 256, 0, stream>>>(
      rowptr, spack, hb, out, kN);
}